// Round 10
// baseline (147.769 us; speedup 1.0000x reference)
//
#include <hip/hip_runtime.h>
#include <hip/hip_bf16.h>
#include <cstdint>
#include <cstddef>

// B=8192, CIN=16, 6x6->5x5 (k=2 VALID), FM=64, DK=DV=NH=32 (dkh=1), HID=128, OUT=5.
// R26 = R25 (verified 147.5 us total, kf ~70 us) + s_setprio(1) around phase-A MFMA
// clusters ONLY (T5: +4-7% in independent-wave no-barrier regime per m191; NOT
// applied to the barrier-locked dense chain, where m190 showed it hurts).
// Final-round ledger: occupancy pinned at 8 waves/CU (unified VGPR+AGPR ~150 ->
// 256-reg granule; forcing <=128 spills catastrophically; LDS 160KB -> 1 block/CU);
// scheduling + code-size levers measured null; remaining ~77 us is harness fills/gaps.
// kf: k1+k2 fused (256 blocks x 512 thr, 32 batches/block).
//  - phase A: per-wave barrier-free pipeline (private 7KB scratch, packed-fp32
//    attention, raw v_exp_f32, log2e pre-scaled k), 4 batches/wave sequential,
//    x prefetched into regs one batch ahead; act rows -> LDS [32][1608] bf16.
//  - one __syncthreads(), then the R2-proven dense chain with A read from LDS.
// LDS total = 102912 + 8*7168 = 160256 <= 160KiB (dynamic, via FuncSetAttribute).

typedef __attribute__((ext_vector_type(4))) float f32x4;
typedef __attribute__((ext_vector_type(2))) float f32x2;
typedef __attribute__((ext_vector_type(8))) __bf16 bf16x8;
typedef __attribute__((ext_vector_type(4))) __bf16 bf16x4;

#define LOG2E 1.4426950408889634f
#define ACT_STRIDE 1608                        // elems (bf16); 3216 B/row
#define ACT_LDS_BYTES (32 * ACT_STRIDE * 2)    // 102912
#define SCRATCH_OFF ACT_LDS_BYTES
#define LDS_TOTAL (ACT_LDS_BYTES + 8 * 7168)   // 160256

// raw v_exp_f32 (2^x) — exp2f() lowers to the OCML wrapper (~4 extra VALU ops).
__device__ __forceinline__ float fast_exp2(float x) {
#if __has_builtin(__builtin_amdgcn_exp2f)
  return __builtin_amdgcn_exp2f(x);
#else
  return __expf(x * 0.6931471805599453f);
#endif
}

// v_mfma_f32_16x16x32_bf16 (bench-verified layout R2-R25):
// A: lane holds A[m=lane&15][k=quad*8+j]; B: W[n=lane&15][k=quad*8+j];
// C/D: col=lane&15, row=quad*4+reg.
__device__ __forceinline__ f32x4 mfma16(bf16x8 a, bf16x8 b, f32x4 c) {
  return __builtin_amdgcn_mfma_f32_16x16x32_bf16(a, b, c, 0, 0, 0);
}

// ---------------- prep: EVERYTHING kf reads (147 tiny parallel blocks) ----------------
__global__ __launch_bounds__(64) void prep(
    const float* __restrict__ conv_w, const float* __restrict__ conv_b,
    const float* __restrict__ qkv_w,  const float* __restrict__ qkv_b,
    const float* __restrict__ attn_w,
    const float* __restrict__ w1, const float* __restrict__ w2,
    __hip_bfloat16* __restrict__ wqb, float* __restrict__ biasb,
    __hip_bfloat16* __restrict__ wab,
    __hip_bfloat16* __restrict__ w1bp, __hip_bfloat16* __restrict__ w2b) {
  const int t = threadIdx.x, tb = blockIdx.x;
  if (tb < 16) {
#pragma unroll
    for (int j = 0; j < 8; ++j) {
      int i = tb * 512 + j * 64 + t;
      float w = (i < 2048) ? conv_w[i] : qkv_w[i - 2048];
      if (i >= 4096 && i < 6144) w *= LOG2E;  // k-channel rows 64..95
      wqb[i] = __float2bfloat16(w);
    }
  } else if (tb == 16) {
#pragma unroll
    for (int j = 0; j < 16; ++j) wab[j * 64 + t] = __float2bfloat16(attn_w[j * 64 + t]);
    for (int i = t; i < 128; i += 64) {
      float b = (i < 32) ? conv_b[i] : qkv_b[i - 32];
      if (i >= 64 && i < 96) b *= LOG2E;
      biasb[i] = b;
    }
  } else if (tb < 145) {
    // w1bp row u: coalesced fp32 read -> LDS -> coalesced permuted bf16 write.
    // single wave: same-wave LDS RAW ordered by lgkmcnt (no barrier needed)
    const int u = tb - 17;
    __shared__ float rowf[1600];
    const float* wr = w1 + u * 1600;
#pragma unroll
    for (int j = 0; j < 25; ++j) rowf[j * 64 + t] = wr[j * 64 + t];
    __hip_bfloat16* wo = w1bp + u * 1600;
#pragma unroll
    for (int j = 0; j < 25; ++j) {
      // read lds[t*25+j]: stride-25 dwords, gcd(25,32)=1 -> conflict-free
      wo[j * 64 + t] = __float2bfloat16(rowf[t * 25 + j]);
    }
  } else {  // tb = 145,146: w2b cast, 4096 elems each
#pragma unroll
    for (int j = 0; j < 64; ++j) {
      int i = (tb - 145) * 4096 + j * 64 + t;
      w2b[i] = __float2bfloat16(w2[i]);
    }
  }
}

// ---------------- kf: fully fused conv+qkv GEMM + attention + 1x1 conv + dense ----------------
__global__ __launch_bounds__(512) void kf(
    const float* __restrict__ x,
    const float* __restrict__ biasb,
    const __hip_bfloat16* __restrict__ wqb,
    const __hip_bfloat16* __restrict__ wab, const float* __restrict__ attn_b,
    const __hip_bfloat16* __restrict__ w1bp, const float* __restrict__ b1,
    const __hip_bfloat16* __restrict__ w2b, const float* __restrict__ b2,
    const float* __restrict__ w3, const float* __restrict__ b3,
    float* __restrict__ out) {
  extern __shared__ __align__(16) char lds_all[];
  const int t = threadIdx.x & 63;   // lane within wave
  const int wv = threadIdx.x >> 6;  // wave 0..7
  const int l15 = t & 15, quad = t >> 4;

  __hip_bfloat16* act_lds = (__hip_bfloat16*)lds_all;   // [32][ACT_STRIDE]
  char* my = lds_all + SCRATCH_OFF + wv * 7168;         // private per-wave region
  __bf16* xs  = (__bf16*)my;          // phase 1 (576 elems)
  __bf16* as_ = (__bf16*)my;          // phase 2/3 (800 elems, stride 32)
  __bf16* qs  = (__bf16*)(my + 1600); // q:0-31 k:32-63(x log2e) v:64-95, stride 28

  // ---- batch-invariant operand frags (hoisted out of the batch loop) ----
  bf16x8 bfr[8][2];
#pragma unroll
  for (int nt = 0; nt < 8; ++nt)
#pragma unroll
    for (int ks = 0; ks < 2; ++ks)
      bfr[nt][ks] = *(const bf16x8*)((const __bf16*)wqb + (nt * 16 + l15) * 64 + ks * 32 + quad * 8);
  float bias[8];
#pragma unroll
  for (int nt = 0; nt < 8; ++nt) bias[nt] = biasb[nt * 16 + l15];
  bf16x8 bw[2]; float ab[2];
#pragma unroll
  for (int nt2 = 0; nt2 < 2; ++nt2) {
    int n = nt2 * 16 + l15;
    bw[nt2] = *(const bf16x8*)((const __bf16*)wab + n * 32 + quad * 8);
    ab[nt2] = attn_b[n];
  }

  const int b_base = blockIdx.x * 32 + wv * 4;

  // ---- x prefetch for first batch (regs; HBM latency hides under prior work) ----
  float xr[9];
  {
    const float* xb = x + (size_t)b_base * 576;
#pragma unroll
    for (int i = 0; i < 9; ++i) xr[i] = xb[t + i * 64];
  }

  for (int it = 0; it < 4; ++it) {
    const int rowoff = (wv * 4 + it) * ACT_STRIDE;

    // ---- stage x -> bf16 LDS (same-wave LDS ordering; no barrier) ----
#pragma unroll
    for (int i = 0; i < 9; ++i) xs[t + i * 64] = __float2bfloat16(xr[i]);

    // ---- phase 1: implicit GEMM, M=25, N=128, K=64; 2 m-tiles sequential ----
#pragma unroll
    for (int mt = 0; mt < 2; ++mt) {
      int row = mt * 16 + l15;
      int pos = row < 24 ? row : 24;
      int ii = pos / 5, jj = pos - ii * 5;
      const __bf16* xp = xs + ii * 6 + jj;
      bf16x8 af[2];
#pragma unroll
      for (int ks = 0; ks < 2; ++ks) {
        const __bf16* p0 = xp + (ks * 8 + quad * 2) * 36;
        bf16x8 a;
        a[0] = p0[0];  a[1] = p0[1];  a[2] = p0[6];  a[3] = p0[7];
        a[4] = p0[36]; a[5] = p0[37]; a[6] = p0[42]; a[7] = p0[43];
        af[ks] = a;
      }
      f32x4 acc[8];
#pragma unroll
      for (int nt = 0; nt < 8; ++nt) acc[nt] = (f32x4){0.f, 0.f, 0.f, 0.f};
      // T5: independent-wave regime (no barriers in phase A) — boost MFMA wave
      __builtin_amdgcn_s_setprio(1);
#pragma unroll
      for (int ks = 0; ks < 2; ++ks)
#pragma unroll
        for (int nt = 0; nt < 8; ++nt)
          acc[nt] = mfma16(af[ks], bfr[nt][ks], acc[nt]);
      __builtin_amdgcn_s_setprio(0);

#pragma unroll
      for (int r = 0; r < 4; ++r) {
        int orow = mt * 16 + quad * 4 + r;
        if (orow < 25) {
#pragma unroll
          for (int nt = 0; nt < 8; ++nt) {
            float v = acc[nt][r] + bias[nt];
            if (nt < 2) {  // conv_out ch 0..31 -> act LDS with relu
              act_lds[rowoff + orow * 64 + nt * 16 + l15] =
                  __float2bfloat16(fmaxf(v, 0.f));
            } else {       // qkv ch 0..95 -> LDS (k already log2e-scaled)
              qs[((nt - 2) * 16 + l15) * 28 + orow] = __float2bfloat16(v);
            }
          }
        }
      }
    }

    // ---- prefetch next batch's x (overlaps with phase 2/3 compute) ----
    if (it < 3) {
      const float* xb = x + (size_t)(b_base + it + 1) * 576;
#pragma unroll
      for (int i = 0; i < 9; ++i) xr[i] = xb[t + i * 64];
    }

    // ---- phase 2: attention, dkh=1; e = 2^(q * k*log2e) via raw v_exp_f32.
    //      PACKED inner loop: 4 packed + 1 scalar acc chains. ----
    {
      const int n = t & 31, half = t >> 5;
      const __bf16* qp = qs + n * 28;
      const __bf16* kp = qs + (32 + n) * 28;
      const __bf16* vp = qs + (64 + n) * 28;
      f32x2 kl2[12], vv2[12];
      float kl24, vv24;
#pragma unroll
      for (int c4 = 0; c4 < 6; ++c4) {
        bf16x4 bb = *(const bf16x4*)(kp + c4 * 4);
        bf16x4 cc = *(const bf16x4*)(vp + c4 * 4);
        kl2[c4 * 2]     = (f32x2){(float)bb[0], (float)bb[1]};
        kl2[c4 * 2 + 1] = (f32x2){(float)bb[2], (float)bb[3]};
        vv2[c4 * 2]     = (f32x2){(float)cc[0], (float)cc[1]};
        vv2[c4 * 2 + 1] = (f32x2){(float)cc[2], (float)cc[3]};
      }
      kl24 = (float)kp[24]; vv24 = (float)vp[24];

      const int i0 = half * 12;
      float qv[13];
      {
        const __bf16* qbase = qp + i0;  // 8B-aligned for i0 in {0,12}
        bf16x4 q0 = *(const bf16x4*)(qbase);
        bf16x4 q1 = *(const bf16x4*)(qbase + 4);
        bf16x4 q2 = *(const bf16x4*)(qbase + 8);
#pragma unroll
        for (int z = 0; z < 4; ++z) {
          qv[z] = (float)q0[z]; qv[4 + z] = (float)q1[z]; qv[8 + z] = (float)q2[z];
        }
        qv[12] = (float)qbase[12];
      }

#pragma unroll
      for (int z = 0; z < 13; ++z) {
        const float qi = qv[z];
        const f32x2 qi2 = {qi, qi};
        f32x2 sA = {0.f, 0.f}, sB = {0.f, 0.f};
        f32x2 oA = {0.f, 0.f}, oB = {0.f, 0.f};
        float s4 = 0.f, o4 = 0.f;
#pragma unroll
        for (int p = 0; p < 6; ++p) {
          f32x2 mA = qi2 * kl2[p];          // v_pk_mul_f32
          f32x2 mB = qi2 * kl2[p + 6];
          f32x2 eA = {fast_exp2(mA.x), fast_exp2(mA.y)};
          f32x2 eB = {fast_exp2(mB.x), fast_exp2(mB.y)};
          sA += eA;                          // v_pk_add_f32
          sB += eB;
          oA = eA * vv2[p] + oA;             // v_pk_fma_f32
          oB = eB * vv2[p + 6] + oB;
        }
        {
          float e = fast_exp2(qi * kl24);
          s4 += e;
          o4 = __builtin_fmaf(e, vv24, o4);
        }
        float ss = ((sA.x + sA.y) + (sB.x + sB.y)) + s4;
        float oo = ((oA.x + oA.y) + (oB.x + oB.y)) + o4;
        as_[(i0 + z) * 32 + n] = __float2bfloat16(oo * __builtin_amdgcn_rcpf(ss));
      }
    }

    // ---- phase 3: 1x1 conv via MFMA. M=25 rows, K=32 heads, N=32 ----
    {
#pragma unroll
      for (int mt = 0; mt < 2; ++mt) {
        int row = mt * 16 + l15;
        int rc = row < 24 ? row : 24;
        bf16x8 af = *(const bf16x8*)(as_ + rc * 32 + quad * 8);
        f32x4 acc[2];
        __builtin_amdgcn_s_setprio(1);
#pragma unroll
        for (int nt2 = 0; nt2 < 2; ++nt2)
          acc[nt2] = mfma16(af, bw[nt2], (f32x4){0.f, 0.f, 0.f, 0.f});
        __builtin_amdgcn_s_setprio(0);
#pragma unroll
        for (int r = 0; r < 4; ++r) {
          int orow = mt * 16 + quad * 4 + r;
          if (orow < 25) {
#pragma unroll
            for (int nt2 = 0; nt2 < 2; ++nt2)
              act_lds[rowoff + orow * 64 + 32 + nt2 * 16 + l15] =
                  __float2bfloat16(fmaxf(acc[nt2][r] + ab[nt2], 0.f));
          }
        }
      }
    }
  }  // batch loop

  __syncthreads();

  // ================= dense chain (R2-proven 32-row/2-acc shape, A from LDS) =================
  // NOTE: no setprio here — barrier-locked lockstep regime, where m190 showed it hurts.
  const int wave = threadIdx.x >> 6;
  const int wm = wave >> 2;  // 0..1
  const int wn = wave & 3;   // 0..3
  const int b0 = blockIdx.x * 32;

  __hip_bfloat16* C1s = (__hip_bfloat16*)(lds_all + SCRATCH_OFF);         // 32*136*2 = 8704 B
  __hip_bfloat16* C2s = (__hip_bfloat16*)(lds_all + SCRATCH_OFF + 8704);  // 32*72*2 = 4608 B

  // ---- layer 1: [32,1600](LDS) x [128,1600]^T ----
  f32x4 acc0 = {0.f, 0.f, 0.f, 0.f};
  f32x4 acc1 = {0.f, 0.f, 0.f, 0.f};
  {
    const __bf16* aL    = (const __bf16*)act_lds + (wm * 16 + l15) * ACT_STRIDE + quad * 8;
    const __bf16* bptr0 = (const __bf16*)w1bp + (size_t)(wn * 32 + l15) * 1600 + quad * 8;
    const __bf16* bptr1 = bptr0 + 16 * 1600;
#pragma unroll 5
    for (int k0 = 0; k0 < 1600; k0 += 32) {
      bf16x8 av  = *(const bf16x8*)(aL + k0);      // ds_read_b128, 2-way max
      bf16x8 bv0 = *(const bf16x8*)(bptr0 + k0);
      bf16x8 bv1 = *(const bf16x8*)(bptr1 + k0);
      acc0 = mfma16(av, bv0, acc0);
      acc1 = mfma16(av, bv1, acc1);
    }
  }
  {
    const int col0 = wn * 32 + l15;
    const float bias0 = b1[col0];
    const float bias1 = b1[col0 + 16];
#pragma unroll
    for (int r = 0; r < 4; ++r) {
      const int row = wm * 16 + quad * 4 + r;
      C1s[row * 136 + col0]      = __float2bfloat16(fmaxf(acc0[r] + bias0, 0.f));
      C1s[row * 136 + col0 + 16] = __float2bfloat16(fmaxf(acc1[r] + bias1, 0.f));
    }
  }
  __syncthreads();

  // ---- layer 2: [32,128] x [64,128]^T ----
  f32x4 acc2 = {0.f, 0.f, 0.f, 0.f};
  {
    const __bf16* aL = (const __bf16*)C1s + (wm * 16 + l15) * 136 + quad * 8;
    const __bf16* bL = (const __bf16*)w2b + (wn * 16 + l15) * 128 + quad * 8;
#pragma unroll
    for (int k0 = 0; k0 < 128; k0 += 32)
      acc2 = mfma16(*(const bf16x8*)(aL + k0), *(const bf16x8*)(bL + k0), acc2);
  }
  {
    const int col = wn * 16 + l15;
    const float bias = b2[col];
#pragma unroll
    for (int r = 0; r < 4; ++r) {
      const int row = wm * 16 + quad * 4 + r;
      C2s[row * 72 + col] = __float2bfloat16(fmaxf(acc2[r] + bias, 0.f));
    }
  }
  __syncthreads();

  // ---- layer 3 (scalar, 160 outputs) ----
  if (threadIdx.x < 160) {
    const int row = threadIdx.x / 5;
    const int oc = threadIdx.x - row * 5;
    float s = b3[oc];
#pragma unroll
    for (int k = 0; k < 64; ++k)
      s += __bfloat162float(C2s[row * 72 + k]) * w3[oc * 64 + k];
    out[(size_t)(b0 + row) * 5 + oc] = s;
  }
}

extern "C" void kernel_launch(void* const* d_in, const int* in_sizes, int n_in,
                              void* d_out, int out_size, void* d_ws, size_t ws_size,
                              hipStream_t stream) {
  const float* x      = (const float*)d_in[0];
  const float* conv_w = (const float*)d_in[1];
  const float* conv_b = (const float*)d_in[2];
  const float* qkv_w  = (const float*)d_in[3];
  const float* qkv_b  = (const float*)d_in[4];
  const float* attn_w = (const float*)d_in[5];
  const float* attn_b = (const float*)d_in[6];
  const float* w1 = (const float*)d_in[7];
  const float* b1 = (const float*)d_in[8];
  const float* w2 = (const float*)d_in[9];
  const float* b2 = (const float*)d_in[10];
  const float* w3 = (const float*)d_in[11];
  const float* b3 = (const float*)d_in[12];
  float* out = (float*)d_out;

  // workspace layout (16B-aligned):
  //   w1bp  [128][1600] bf16 : 409,600 B  (K pre-permuted to [pos][ch])
  //   w2b   [64][128]   bf16 :  16,384 B
  //   wqb   [128][64]   bf16 :  16,384 B  (k rows pre-scaled by log2e)
  //   biasb [128]       f32  :     512 B  (k entries pre-scaled by log2e)
  //   wab   [32][32]    bf16 :   2,048 B
  char* ws = (char*)d_ws;
  __hip_bfloat16* w1bp  = (__hip_bfloat16*)ws;
  __hip_bfloat16* w2b   = (__hip_bfloat16*)(ws + 409600);
  __hip_bfloat16* wqb   = (__hip_bfloat16*)(ws + 425984);
  float*          biasb = (float*)(ws + 442368);
  __hip_bfloat16* wab   = (__hip_bfloat16*)(ws + 442880);

  hipFuncSetAttribute(reinterpret_cast<const void*>(kf),
                      hipFuncAttributeMaxDynamicSharedMemorySize, LDS_TOTAL);

  prep<<<dim3(147), dim3(64), 0, stream>>>(conv_w, conv_b, qkv_w, qkv_b, attn_w,
                                           w1, w2, wqb, biasb, wab, w1bp, w2b);
  kf<<<dim3(256), dim3(512), LDS_TOTAL, stream>>>(x, biasb, wqb, wab, attn_b,
                                                  w1bp, b1, w2b, b2, w3, b3, out);
}